// Round 1
// baseline (667.037 us; speedup 1.0000x reference)
//
#include <hip/hip_runtime.h>

#define N_NODES 100000
#define N_EDGES 1600000
#define N_GRAPHS 64
#define DIM 128
#define BN_EPS 1e-5f
#define EPAD 2000000          // sentinel-filled esrc capacity (needs 1,903,419)

#define NB_SENT 977           // esrc sentinel fill, 8 per thread
#define NB_WPREP 192          // 3*128*128/256
#define NB_HIST 391           // coarse hist: 391 chunks * 4096 edges
#define NB_ZERO 40            // zero scratch: 40*256 = 10240 words >= zwords
#define NBUCK 782             // coarse buckets = id>>7 (100000/128)
#define NG (NBUCK * NB_HIST)  // per-side count-matrix size = 305762
#define NB_SCANG2 2389        // ceil(2*NG/256)
#define BUCK_RESERVE 388      // cnt + 128*3 pad + 4 align slack

#define AT_STRIDE 136  // 128 + 8 pad: 2-way-only LDS bank aliasing

typedef unsigned short ushort_t;
typedef unsigned char uchar_t;
typedef unsigned int uint_t;
typedef __attribute__((ext_vector_type(8))) short bf16x8;
typedef __attribute__((ext_vector_type(4))) float f32x4;

__device__ __forceinline__ float bfl(uint_t u) {
    union { uint_t i; float f; } v; v.i = u << 16; return v.f;
}
__device__ __forceinline__ float bfh(uint_t u) {
    union { uint_t i; float f; } v; v.i = u & 0xffff0000u; return v.f;
}
__device__ __forceinline__ ushort_t f2bf(float f) {
    union { float f; uint_t i; } v; v.f = f;
    uint_t x = v.i;
    return (ushort_t)((x + 0x7fffu + ((x >> 16) & 1u)) >> 16);
}
__device__ __forceinline__ uint_t pack2(float lo, float hi) {
    return ((uint_t)f2bf(hi) << 16) | (uint_t)f2bf(lo);
}

// ---------------- front mega-kernel: {sentinel | wprep | dual coarse-hist | zero} ----------------
__global__ void k_front(const int* __restrict__ src, const int* __restrict__ dst,
                        ushort_t* __restrict__ bufA, int* __restrict__ esrc,
                        const float* __restrict__ w1, const float* __restrict__ w2,
                        const float* __restrict__ w3, ushort_t* __restrict__ wbt,
                        int* __restrict__ GG, int* __restrict__ zp, int zwords) {
    __shared__ int hh[NBUCK];
    __shared__ int hh2[NBUCK];
    int b = blockIdx.x;
    int t = threadIdx.x;
    if (b < NB_SENT) {  // esrc sentinel fill + zero bufA sentinel feature row
        int i0 = (b * 256 + t) * 8;
        int4 sv = make_int4(N_NODES, N_NODES, N_NODES, N_NODES);
        if (i0 + 8 <= EPAD) {
            *(int4*)(esrc + i0) = sv;
            *(int4*)(esrc + i0 + 4) = sv;
        } else {
            for (int i = i0; i < EPAD; ++i) esrc[i] = N_NODES;
        }
        if (b == 0 && t < 64)
            ((uint_t*)(bufA + (size_t)N_NODES * DIM))[t] = 0u;
        return;
    }
    b -= NB_SENT;
    if (b < NB_WPREP) {  // W fp32 [k][n] -> bf16 transposed [n][k]
        int i = b * 256 + t;
        int l = i >> 14;
        int idx = i & (DIM * DIM - 1);
        int n = idx >> 7, k = idx & (DIM - 1);
        const float* wsrc = (l == 0) ? w1 : (l == 1) ? w2 : w3;
        wbt[i] = f2bf(wsrc[k * DIM + n]);
        return;
    }
    b -= NB_WPREP;
    if (b < NB_HIST) {  // dual coarse histogram (dst>>7 and src>>7): 4096 edges/chunk
        for (int k = t; k < NBUCK; k += 256) { hh[k] = 0; hh2[k] = 0; }
        __syncthreads();
        int e0 = b * 4096;
        int e1 = min(e0 + 4096, N_EDGES);
        for (int i = e0 + t; i < e1; i += 256) {
            atomicAdd(&hh[dst[i] >> 7], 1);
            atomicAdd(&hh2[src[i] >> 7], 1);
        }
        __syncthreads();
        for (int k = t; k < NBUCK; k += 256) {
            GG[k * NB_HIST + b] = hh[k];
            GG[NG + k * NB_HIST + b] = hh2[k];
        }
        return;
    }
    b -= NB_HIST;
    {  // zero scratch region (bnsum/bnsq/pool/cnt)
        int i = b * 256 + t;
        if (i < zwords) zp[i] = 0;
    }
}

// ---------------- scan of GG (both sides concatenated) -> exclusive Gs ----------------
__global__ void k_scanA(const int* __restrict__ GG, int* __restrict__ Gs,
                        int* __restrict__ partials) {
    __shared__ int s[256];
    int t = threadIdx.x;
    int i = blockIdx.x * 256 + t;
    int v = (i < 2 * NG) ? GG[i] : 0;
    s[t] = v;
    __syncthreads();
    for (int off = 1; off < 256; off <<= 1) {
        int add = (t >= off) ? s[t - off] : 0;
        __syncthreads();
        s[t] += add;
        __syncthreads();
    }
    if (i < 2 * NG) Gs[i + 1] = s[t];
    if (t == 255) partials[blockIdx.x] = s[t];
}

__global__ void k_scanB(const int* __restrict__ partials, int* __restrict__ Gs) {
    __shared__ int s[256];
    int t = threadIdx.x;
    int p = 0;
    for (int j = t; j < (int)blockIdx.x; j += 256) p += partials[j];
    s[t] = p;
    __syncthreads();
    for (int off = 128; off > 0; off >>= 1) {
        if (t < off) s[t] += s[t + off];
        __syncthreads();
    }
    int prefix = s[0];
    int i = blockIdx.x * 256 + t;
    if (i < 2 * NG) Gs[i + 1] += prefix;
    if (blockIdx.x == 0 && t == 0) Gs[0] = 0;
}

// ---------------- pass 2: coarse scatter. dst side: packed (src | dl<<17) uint;
// src side: fine-bin bytes (Cls). ----------------
__global__ void k_pass2(const int* __restrict__ src, const int* __restrict__ dst,
                        const int* __restrict__ Gs, uint_t* __restrict__ Cpk,
                        uchar_t* __restrict__ Cls) {
    __shared__ int cur[NBUCK];
    __shared__ int cur2[NBUCK];
    int b = blockIdx.x;  // 391 blocks
    int t = threadIdx.x;
    for (int k = t; k < NBUCK; k += 256) {
        cur[k] = Gs[k * NB_HIST + b];
        cur2[k] = Gs[NG + k * NB_HIST + b] - N_EDGES;
    }
    __syncthreads();
    int e0 = b * 4096;
    int e1 = min(e0 + 4096, N_EDGES);
    for (int i = e0 + t; i < e1; i += 256) {
        int d = dst[i];
        int s = src[i];
        int slot = atomicAdd(&cur[d >> 7], 1);
        Cpk[slot] = (uint_t)s | ((uint_t)(d & 127) << 17);
        int slot2 = atomicAdd(&cur2[s >> 7], 1);
        Cls[slot2] = (uchar_t)(s & 127);
    }
}

// ---------------- pass 3, dual partition:
// blocks [0,NBUCK): dst-side fine build (rowptr/pdeg/nd + esrc)
// blocks [NBUCK,2*NBUCK): src-side fine histogram -> ns, then fused embed+prescale ----------------
__global__ void k_fine(const uint_t* __restrict__ Cpk, const uchar_t* __restrict__ Cls,
                       const int* __restrict__ Gs,
                       const int* __restrict__ tokens, const float* __restrict__ embed,
                       int* __restrict__ esrc, int* __restrict__ rowptr,
                       int* __restrict__ pdeg, float* __restrict__ ns,
                       float* __restrict__ nd, ushort_t* __restrict__ bufA) {
    __shared__ int hcnt[128];
    __shared__ int hstart[128];
    __shared__ float lns[128];
    int b = blockIdx.x;
    int t = threadIdx.x;
    if (b < NBUCK) {  // dst side
        int k = b;
        int node0 = k * 128;
        int nn = min(128, N_NODES - node0);
        int S = Gs[k * NB_HIST];
        int E = Gs[(k + 1) * NB_HIST];
        if (t < 128) hcnt[t] = 0;
        __syncthreads();
        for (int i = S + t; i < E; i += 256) atomicAdd(&hcnt[Cpk[i] >> 17], 1);
        __syncthreads();
        if (t == 0) {
            int acc = 0;
            for (int n = 0; n < nn; ++n) {
                hstart[n] = acc;
                acc += (hcnt[n] + 3) & ~3;
            }
        }
        __syncthreads();
        int base = (k * BUCK_RESERVE + S + 3) & ~3;
        if (t < nn) {
            int node = node0 + t;
            rowptr[node] = base + hstart[t];
            pdeg[node] = (hcnt[t] + 3) & ~3;
            nd[node] = rsqrtf(fmaxf((float)hcnt[t], 1.0f));
        }
        __syncthreads();
        for (int i = S + t; i < E; i += 256) {
            uint_t pk = Cpk[i];
            int slot = atomicAdd(&hstart[pk >> 17], 1);
            esrc[base + slot] = (int)(pk & 0x1FFFFu);
        }
    } else {  // src side -> ns, then fused embed gather + l0 prescale
        int k = b - NBUCK;
        int node0 = k * 128;
        int nn = min(128, N_NODES - node0);
        int S = Gs[NG + k * NB_HIST] - N_EDGES;
        int E = Gs[NG + (k + 1) * NB_HIST] - N_EDGES;
        if (t < 128) hcnt[t] = 0;
        __syncthreads();
        for (int i = S + t; i < E; i += 256) atomicAdd(&hcnt[Cls[i]], 1);
        __syncthreads();
        if (t < nn) {
            float v = rsqrtf(fmaxf((float)hcnt[t], 1.0f));
            ns[node0 + t] = v;
            lns[t] = v;
        }
        if (k == 0 && t == 0) ns[N_NODES] = 0.f;  // kills sentinel contributions
        __syncthreads();
        // fused embed + l0 prescale for this block's nodes
        for (int slot = t; slot < nn * 16; slot += 256) {
            int nloc = slot >> 4, sub = slot & 15;
            int node = node0 + nloc;
            float s = lns[nloc];
            const float* ep = embed + (size_t)tokens[node] * DIM + sub * 8;
            float4 a = *(const float4*)ep;
            float4 c = *(const float4*)(ep + 4);
            uint4 o;
            o.x = pack2(a.x * s, a.y * s);
            o.y = pack2(a.z * s, a.w * s);
            o.z = pack2(c.x * s, c.y * s);
            o.w = pack2(c.z * s, c.w * s);
            *(uint4*)(bufA + (size_t)node * DIM + sub * 8) = o;
        }
    }
}

// ---------------- prescale: x[v] = relu(fma(y,a,c)) * ns[v], bf16 (BN layers) ----------------
__global__ void k_prescale(const ushort_t* __restrict__ yin, const float* __restrict__ ns,
                           const float* __restrict__ bnsum, const float* __restrict__ bnsq,
                           const float* __restrict__ g, const float* __restrict__ be,
                           ushort_t* __restrict__ xout) {
    __shared__ float sa[DIM], sc[DIM];
    int t = threadIdx.x;
    if (t < DIM) {
        float mu = bnsum[t] * (1.0f / N_NODES);
        float var = bnsq[t] * (1.0f / N_NODES) - mu * mu;
        float rstd = rsqrtf(var + BN_EPS);
        float a = g[t] * rstd;
        sa[t] = a;
        sc[t] = be[t] - mu * a;
    }
    __syncthreads();
    int gid = blockIdx.x * 256 + t;  // 6250 blocks * 256 = N*16 exactly
    int node = gid >> 4, sub = gid & 15;
    float s = ns[node];
    uint4 u = *(const uint4*)(yin + (size_t)node * DIM + sub * 8);
    float v[8] = {bfl(u.x), bfh(u.x), bfl(u.y), bfh(u.y),
                  bfl(u.z), bfh(u.z), bfl(u.w), bfh(u.w)};
    const float* a = sa + sub * 8;
    const float* c = sc + sub * 8;
#pragma unroll
    for (int i = 0; i < 8; ++i) v[i] = fmaxf(fmaf(v[i], a[i], c[i]), 0.f) * s;
    uint4 o;
    o.x = pack2(v[0], v[1]); o.y = pack2(v[2], v[3]);
    o.z = pack2(v[4], v[5]); o.w = pack2(v[6], v[7]);
    *(uint4*)(xout + (size_t)node * DIM + sub * 8) = o;
}

// ---------------- FUSED gather (quad-per-edge dwordx4) -> LDS -> MFMA + BN stats.
// 256-thread blocks, 64 nodes. Lane layout for gather: quad = lane>>4 picks one
// of 4 edges per trip (pdeg is x4-padded => trips = pdeg>>2 exact), m16 = lane&15
// covers 16B of the 256B feature row. One global_load_dwordx4 fetches 4 full
// rows (1KB) per wave-instruction; features are software-pipelined one
// iteration ahead (4 dwordx4 = 16 edges = 4KB in flight sustained), indices
// prefetched ahead of that. Cross-quad reduce via shfl_xor(16/32); quad 0
// packs+writes the LDS row. No barrier between gather and MFMA (rows are
// wave-private). ----------------
__global__ __launch_bounds__(256, 5) void k_agggemm(const ushort_t* __restrict__ hs,
        const int* __restrict__ rowptr, const int* __restrict__ pdeg,
        const int* __restrict__ esrc, const float* __restrict__ nd,
        const ushort_t* __restrict__ wbt, const float* __restrict__ bias,
        ushort_t* __restrict__ y,
        float* __restrict__ bnsum, float* __restrict__ bnsq) {
    __shared__ ushort_t at[64 * AT_STRIDE];
    __shared__ float csum[DIM], csq[DIM];
    int tid = threadIdx.x;
    int wave = tid >> 6;
    int lane = tid & 63;
    if (tid < DIM) { csum[tid] = 0.f; csq[tid] = 0.f; }
    __syncthreads();  // startup-only barrier (waves are ~aligned here; cheap)

    int bnode = blockIdx.x * 64 + wave * 16;
    int quad = lane >> 4;   // edge slot within a trip (0..3)
    int m16 = lane & 15;    // 16B chunk within the 256B row

    const ushort_t* hrow = hs + (size_t)m16 * 8;  // lane's column offset

    // prefetch the wave's 16 row starts + padded degrees, serve via shfl
    int rpv = 0, pdv = 0;
    if (lane < 16) {
        int nnode = bnode + lane;
        if (nnode < N_NODES) { rpv = rowptr[nnode]; pdv = pdeg[nnode]; }
    }

#define FEATLD(ix) (*(const uint4*)(hrow + (size_t)(ix) * DIM))
#define ACCU(F, A)                                                  \
    {                                                               \
        A[0] += bfl((F).x); A[1] += bfh((F).x);                     \
        A[2] += bfl((F).y); A[3] += bfh((F).y);                     \
        A[4] += bfl((F).z); A[5] += bfh((F).z);                     \
        A[6] += bfl((F).w); A[7] += bfh((F).w);                     \
    }
// 2-deep pipelined single-node drain (E: next slot ptr incl. quad, T: trips left)
#define DRAIN(E, T, A)                                              \
    {                                                               \
        if ((T) >= 2) {                                             \
            int i0_ = esrc[E], i1_ = esrc[(E) + 4];                 \
            (E) += 8; (T) -= 2;                                     \
            uint4 f0_ = FEATLD(i0_), f1_ = FEATLD(i1_);             \
            while ((T) >= 2) {                                      \
                int j0_ = esrc[E], j1_ = esrc[(E) + 4];             \
                (E) += 8; (T) -= 2;                                 \
                ACCU(f0_, A); ACCU(f1_, A);                         \
                f0_ = FEATLD(j0_); f1_ = FEATLD(j1_);               \
            }                                                       \
            ACCU(f0_, A); ACCU(f1_, A);                             \
        }                                                           \
        if (T) {                                                    \
            int i0_ = esrc[E];                                      \
            uint4 f0_ = FEATLD(i0_);                                \
            ACCU(f0_, A);                                           \
        }                                                           \
    }

    // ---- phase 1: gather, 2 nodes in flight, 2 trips (8 edges)/node/iter,
    // feature loads pipelined one full iteration ahead ----
    for (int i = 0; i < 16; i += 2) {
        int nodeA = bnode + i;
        int nodeB = bnode + i + 1;
        int eA = __shfl(rpv, i) + quad;
        int tA = __shfl(pdv, i) >> 2;
        int eB = __shfl(rpv, i + 1) + quad;
        int tB = __shfl(pdv, i + 1) >> 2;
        float aA[8] = {0.f, 0.f, 0.f, 0.f, 0.f, 0.f, 0.f, 0.f};
        float aB[8] = {0.f, 0.f, 0.f, 0.f, 0.f, 0.f, 0.f, 0.f};
        if (tA >= 2 && tB >= 2) {
            int iA0 = esrc[eA], iA1 = esrc[eA + 4];
            int iB0 = esrc[eB], iB1 = esrc[eB + 4];
            eA += 8; eB += 8; tA -= 2; tB -= 2;
            uint4 fA0 = FEATLD(iA0), fA1 = FEATLD(iA1);
            uint4 fB0 = FEATLD(iB0), fB1 = FEATLD(iB1);
            while (tA >= 2 && tB >= 2) {
                // next indices first (overlap with the feat wait below)
                int jA0 = esrc[eA], jA1 = esrc[eA + 4];
                int jB0 = esrc[eB], jB1 = esrc[eB + 4];
                eA += 8; eB += 8; tA -= 2; tB -= 2;
                // consume features issued LAST iteration
                ACCU(fA0, aA); ACCU(fA1, aA);
                ACCU(fB0, aB); ACCU(fB1, aB);
                // issue next features (stay in flight across the loop edge)
                fA0 = FEATLD(jA0); fA1 = FEATLD(jA1);
                fB0 = FEATLD(jB0); fB1 = FEATLD(jB1);
            }
            ACCU(fA0, aA); ACCU(fA1, aA);
            ACCU(fB0, aB); ACCU(fB1, aB);
        }
        DRAIN(eA, tA, aA);
        DRAIN(eB, tB, aB);
        // cross-quad reduction: lanes m, m+16, m+32, m+48 hold partials of the
        // same 8 features
#pragma unroll
        for (int j = 0; j < 8; ++j) {
            aA[j] += __shfl_xor(aA[j], 16);
            aA[j] += __shfl_xor(aA[j], 32);
            aB[j] += __shfl_xor(aB[j], 16);
            aB[j] += __shfl_xor(aB[j], 32);
        }
        float nA = (nodeA < N_NODES) ? nd[nodeA] : 0.f;
        float nB = (nodeB < N_NODES) ? nd[nodeB] : 0.f;
        if (quad == 0) {
            uint4 oA, oB;
            oA.x = pack2(aA[0] * nA, aA[1] * nA);
            oA.y = pack2(aA[2] * nA, aA[3] * nA);
            oA.z = pack2(aA[4] * nA, aA[5] * nA);
            oA.w = pack2(aA[6] * nA, aA[7] * nA);
            oB.x = pack2(aB[0] * nB, aB[1] * nB);
            oB.y = pack2(aB[2] * nB, aB[3] * nB);
            oB.z = pack2(aB[4] * nB, aB[5] * nB);
            oB.w = pack2(aB[6] * nB, aB[7] * nB);
            *(uint4*)&at[(wave * 16 + i) * AT_STRIDE + m16 * 8] = oA;
            *(uint4*)&at[(wave * 16 + i + 1) * AT_STRIDE + m16 * 8] = oB;
        }
    }
#undef DRAIN
#undef ACCU
#undef FEATLD
    // NO barrier: each wave's MFMA reads only its own 16 LDS rows.

    // ---- phase 2: MFMA (D: col=lane&15, row=quad*4+reg) ----
    f32x4 acc[8];
#pragma unroll
    for (int nb = 0; nb < 8; ++nb) acc[nb] = (f32x4)(0.f);

    const ushort_t* ap = &at[(wave * 16 + m16) * AT_STRIDE + quad * 8];
#pragma unroll
    for (int k0b = 0; k0b < 4; ++k0b) {
        bf16x8 af = *(const bf16x8*)(ap + k0b * 32);
#pragma unroll
        for (int nb = 0; nb < 8; ++nb) {
            int ncol = nb * 16 + m16;
            bf16x8 bfg = *(const bf16x8*)(wbt + (size_t)ncol * DIM + k0b * 32 + quad * 8);
            acc[nb] = __builtin_amdgcn_mfma_f32_16x16x32_bf16(af, bfg, acc[nb], 0, 0, 0);
        }
    }

    // epilogue: bias, block-shared BN partial stats (LDS atomics), bf16 store
#pragma unroll
    for (int nb = 0; nb < 8; ++nb) {
        int col = nb * 16 + m16;
        float bcol = bias[col];
        float ps = 0.f, pq = 0.f;
#pragma unroll
        for (int reg = 0; reg < 4; ++reg) {
            int r = bnode + quad * 4 + reg;
            if (r < N_NODES) {
                float v = acc[nb][reg] + bcol;
                ps += v; pq += v * v;
                y[(size_t)r * DIM + col] = f2bf(v);
            }
        }
        atomicAdd(&csum[col], ps);
        atomicAdd(&csq[col], pq);
    }
    __syncthreads();  // final barrier: stats complete before global reduce
    if (tid < DIM) {
        atomicAdd(&bnsum[tid], csum[tid]);
        atomicAdd(&bnsq[tid], csq[tid]);
    }
}

// ---------------- pooling: fused layer-3 BN fold+apply + graph counts ----------------
#define POOL_NODES 128
__global__ void k_pool(const ushort_t* __restrict__ yin, const int* __restrict__ gids,
                       const float* __restrict__ bnsum, const float* __restrict__ bnsq,
                       const float* __restrict__ g, const float* __restrict__ be,
                       float* __restrict__ pool, int* __restrict__ cnt) {
    __shared__ int h[N_GRAPHS];
    int col = threadIdx.x;  // 128
    float mu = bnsum[col] * (1.0f / N_NODES);
    float var = bnsq[col] * (1.0f / N_NODES) - mu * mu;
    float rstd = rsqrtf(var + BN_EPS);
    float a = g[col] * rstd;
    float c = be[col] - mu * a;
    if (col < N_GRAPHS) h[col] = 0;
    __syncthreads();
    int base = blockIdx.x * POOL_NODES;
    int end = min(base + POOL_NODES, N_NODES);
    for (int n = base + col; n < end; n += 128) atomicAdd(&h[gids[n]], 1);
    __syncthreads();
    if (col < N_GRAPHS && h[col]) atomicAdd(&cnt[col], h[col]);
    float acc = 0.f;
    int cur = gids[base];
    for (int n = base; n < end; ++n) {
        int gg = gids[n];
        if (gg != cur) {
            atomicAdd(&pool[(size_t)cur * DIM + col], acc);
            acc = 0.f;
            cur = gg;
        }
        uint_t u = *(const uint_t*)(yin + (size_t)n * DIM + (col & ~1));
        float v = (col & 1) ? bfh(u) : bfl(u);
        acc += fmaxf(fmaf(v, a, c), 0.f);
    }
    atomicAdd(&pool[(size_t)cur * DIM + col], acc);
}

// ---------------- final FC (one block per graph) ----------------
__global__ void k_final(const float* __restrict__ pool, const int* __restrict__ cnt,
                        const float* __restrict__ fcW1, const float* __restrict__ fcb1,
                        const float* __restrict__ fcW2, const float* __restrict__ fcb2,
                        float* __restrict__ out) {
    __shared__ float hg[DIM];
    __shared__ float z[64];
    int g = blockIdx.x;
    int t = threadIdx.x;  // 128
    float cf = fmaxf((float)cnt[g], 1.0f);
    hg[t] = pool[(size_t)g * DIM + t] / cf;
    __syncthreads();
    if (t < 64) {
        float acc = fcb1[t];
        for (int k = 0; k < DIM; ++k)
            acc += hg[k] * fcW1[k * 64 + t];
        z[t] = fmaxf(acc, 0.f);
    }
    __syncthreads();
    if (t < 2) {
        float acc = fcb2[t];
        for (int k = 0; k < 64; ++k)
            acc += z[k] * fcW2[k * 2 + t];
        out[g * 2 + t] = acc;
    }
}

extern "C" void kernel_launch(void* const* d_in, const int* in_sizes, int n_in,
                              void* d_out, int out_size, void* d_ws, size_t ws_size,
                              hipStream_t stream) {
    const int* tokens = (const int*)d_in[0];
    const int* src = (const int*)d_in[1];
    const int* dst = (const int*)d_in[2];
    const int* gids = (const int*)d_in[3];
    const float* embed = (const float*)d_in[4];
    const float* W1 = (const float*)d_in[5];
    const float* b1 = (const float*)d_in[6];
    const float* g1 = (const float*)d_in[7];
    const float* be1 = (const float*)d_in[8];
    const float* W2 = (const float*)d_in[9];
    const float* b2 = (const float*)d_in[10];
    const float* g2 = (const float*)d_in[11];
    const float* be2 = (const float*)d_in[12];
    const float* W3 = (const float*)d_in[13];
    const float* b3 = (const float*)d_in[14];
    const float* g3 = (const float*)d_in[15];
    const float* be3 = (const float*)d_in[16];
    const float* fcW1 = (const float*)d_in[17];
    const float* fcb1 = (const float*)d_in[18];
    const float* fcW2 = (const float*)d_in[19];
    const float* fcb2 = (const float*)d_in[20];
    float* out = (float*)d_out;

    char* w = (char*)d_ws;
    auto alloc = [&](size_t bytes) {
        void* p = (void*)w;
        w += (bytes + 255) & ~(size_t)255;
        return p;
    };
    ushort_t* bufH = (ushort_t*)alloc((size_t)(N_NODES + 1) * DIM * 2);  // y2
    ushort_t* bufA = (ushort_t*)alloc((size_t)(N_NODES + 1) * DIM * 2);  // prescaled gather input
    ushort_t* bufY = (ushort_t*)alloc((size_t)(N_NODES + 1) * DIM * 2);  // y1 / y3
    int* esrc = (int*)alloc((size_t)EPAD * 4);
    int* rowptr = (int*)alloc((size_t)N_NODES * 4);
    int* pdeg = (int*)alloc((size_t)N_NODES * 4);
    float* ns = (float*)alloc((size_t)(N_NODES + 1) * 4);
    float* nd = (float*)alloc((size_t)N_NODES * 4);
    ushort_t* wbt = (ushort_t*)alloc(3 * DIM * DIM * 2);
    int* GG = (int*)alloc((size_t)(2 * NG) * 4);
    int* Gs = (int*)alloc((size_t)(2 * NG + 1) * 4);
    int* partials = (int*)alloc(4096 * 4);
    uint_t* Cpk = (uint_t*)alloc((size_t)N_EDGES * 4);
    uchar_t* Cls = (uchar_t*)alloc((size_t)N_EDGES);
    // zeroed region (contiguous)
    char* zstart = w;
    float* bnsum = (float*)alloc(3 * DIM * 4);
    float* bnsq = (float*)alloc(3 * DIM * 4);
    float* pool = (float*)alloc((size_t)N_GRAPHS * DIM * 4);
    int* cnt = (int*)alloc((size_t)N_GRAPHS * 4);
    int zwords = (int)((size_t)(w - zstart) / 4);

    k_front<<<NB_SENT + NB_WPREP + NB_HIST + NB_ZERO, 256, 0, stream>>>(
        src, dst, bufA, esrc, W1, W2, W3, wbt, GG, (int*)zstart, zwords);
    k_scanA<<<NB_SCANG2, 256, 0, stream>>>(GG, Gs, partials);
    k_scanB<<<NB_SCANG2, 256, 0, stream>>>(partials, Gs);
    k_pass2<<<NB_HIST, 256, 0, stream>>>(src, dst, Gs, Cpk, Cls);
    k_fine<<<2 * NBUCK, 256, 0, stream>>>(Cpk, Cls, Gs, tokens, embed,
                                          esrc, rowptr, pdeg, ns, nd, bufA);

    int nb_fused = (N_NODES + 63) / 64;  // 256-thread blocks, 64 nodes each
    int nb_ps = 6250;                    // N*16/256

    // l=0: bufA already holds embed*ns (fused into k_fine); gather -> y1 in bufY
    k_agggemm<<<nb_fused, 256, 0, stream>>>(bufA, rowptr, pdeg, esrc, nd,
                                            wbt, b1, bufY, bnsum, bnsq);
    // l=1: prescale bufY (BN stats1) -> bufA; gather -> y2 in bufH
    k_prescale<<<nb_ps, 256, 0, stream>>>(bufY, ns, bnsum, bnsq, g1, be1, bufA);
    k_agggemm<<<nb_fused, 256, 0, stream>>>(bufA, rowptr, pdeg, esrc, nd,
                                            wbt + (size_t)DIM * DIM, b2, bufH,
                                            bnsum + DIM, bnsq + DIM);
    // l=2: prescale bufH (BN stats2) -> bufA; gather -> y3 in bufY
    k_prescale<<<nb_ps, 256, 0, stream>>>(bufH, ns, bnsum + DIM, bnsq + DIM, g2, be2, bufA);
    k_agggemm<<<nb_fused, 256, 0, stream>>>(bufA, rowptr, pdeg, esrc, nd,
                                            wbt + (size_t)2 * DIM * DIM, b3, bufY,
                                            bnsum + 2 * DIM, bnsq + 2 * DIM);

    k_pool<<<(N_NODES + POOL_NODES - 1) / POOL_NODES, DIM, 0, stream>>>(
        bufY, gids, bnsum + 2 * DIM, bnsq + 2 * DIM, g3, be3, pool, cnt);
    k_final<<<N_GRAPHS, DIM, 0, stream>>>(pool, cnt, fcW1, fcb1, fcW2, fcb2, out);
}

// Round 2
// 604.041 us; speedup vs baseline: 1.1043x; 1.1043x over previous
//
#include <hip/hip_runtime.h>

#define N_NODES 100000
#define N_EDGES 1600000
#define N_GRAPHS 64
#define DIM 128
#define BN_EPS 1e-5f
#define EPAD 2000000          // sentinel-filled esrc capacity (needs 1,903,419 + prefetch slack)

#define NB_SENT 977           // esrc sentinel fill, 8 per thread
#define NB_WPREP 192          // 3*128*128/256
#define NB_HIST 391           // coarse hist: 391 chunks * 4096 edges
#define NB_ZERO 40            // zero scratch: 40*256 = 10240 words >= zwords
#define NBUCK 782             // coarse buckets = id>>7 (100000/128)
#define NG (NBUCK * NB_HIST)  // per-side count-matrix size = 305762
#define NB_SCANG2 2389        // ceil(2*NG/256)
#define BUCK_RESERVE 388      // cnt + 128*3 pad + 4 align slack

#define AT_STRIDE 136  // 128 + 8 pad: 2-way-only LDS bank aliasing

typedef unsigned short ushort_t;
typedef unsigned char uchar_t;
typedef unsigned int uint_t;
typedef __attribute__((ext_vector_type(8))) short bf16x8;
typedef __attribute__((ext_vector_type(4))) float f32x4;

__device__ __forceinline__ float bfl(uint_t u) {
    union { uint_t i; float f; } v; v.i = u << 16; return v.f;
}
__device__ __forceinline__ float bfh(uint_t u) {
    union { uint_t i; float f; } v; v.i = u & 0xffff0000u; return v.f;
}
__device__ __forceinline__ ushort_t f2bf(float f) {
    union { float f; uint_t i; } v; v.f = f;
    uint_t x = v.i;
    return (ushort_t)((x + 0x7fffu + ((x >> 16) & 1u)) >> 16);
}
__device__ __forceinline__ uint_t pack2(float lo, float hi) {
    return ((uint_t)f2bf(hi) << 16) | (uint_t)f2bf(lo);
}

// ---------------- front mega-kernel: {sentinel | wprep | dual coarse-hist | zero} ----------------
__global__ void k_front(const int* __restrict__ src, const int* __restrict__ dst,
                        ushort_t* __restrict__ bufA, int* __restrict__ esrc,
                        const float* __restrict__ w1, const float* __restrict__ w2,
                        const float* __restrict__ w3, ushort_t* __restrict__ wbt,
                        int* __restrict__ GG, int* __restrict__ zp, int zwords) {
    __shared__ int hh[NBUCK];
    __shared__ int hh2[NBUCK];
    int b = blockIdx.x;
    int t = threadIdx.x;
    if (b < NB_SENT) {  // esrc sentinel fill + zero bufA sentinel feature row
        int i0 = (b * 256 + t) * 8;
        int4 sv = make_int4(N_NODES, N_NODES, N_NODES, N_NODES);
        if (i0 + 8 <= EPAD) {
            *(int4*)(esrc + i0) = sv;
            *(int4*)(esrc + i0 + 4) = sv;
        } else {
            for (int i = i0; i < EPAD; ++i) esrc[i] = N_NODES;
        }
        if (b == 0 && t < 64)
            ((uint_t*)(bufA + (size_t)N_NODES * DIM))[t] = 0u;
        return;
    }
    b -= NB_SENT;
    if (b < NB_WPREP) {  // W fp32 [k][n] -> bf16 transposed [n][k]
        int i = b * 256 + t;
        int l = i >> 14;
        int idx = i & (DIM * DIM - 1);
        int n = idx >> 7, k = idx & (DIM - 1);
        const float* wsrc = (l == 0) ? w1 : (l == 1) ? w2 : w3;
        wbt[i] = f2bf(wsrc[k * DIM + n]);
        return;
    }
    b -= NB_WPREP;
    if (b < NB_HIST) {  // dual coarse histogram (dst>>7 and src>>7): 4096 edges/chunk
        for (int k = t; k < NBUCK; k += 256) { hh[k] = 0; hh2[k] = 0; }
        __syncthreads();
        int e0 = b * 4096;
        int e1 = min(e0 + 4096, N_EDGES);
        for (int i = e0 + t; i < e1; i += 256) {
            atomicAdd(&hh[dst[i] >> 7], 1);
            atomicAdd(&hh2[src[i] >> 7], 1);
        }
        __syncthreads();
        for (int k = t; k < NBUCK; k += 256) {
            GG[k * NB_HIST + b] = hh[k];
            GG[NG + k * NB_HIST + b] = hh2[k];
        }
        return;
    }
    b -= NB_HIST;
    {  // zero scratch region (bnsum/bnsq/pool/cnt)
        int i = b * 256 + t;
        if (i < zwords) zp[i] = 0;
    }
}

// ---------------- scan of GG (both sides concatenated) -> exclusive Gs ----------------
__global__ void k_scanA(const int* __restrict__ GG, int* __restrict__ Gs,
                        int* __restrict__ partials) {
    __shared__ int s[256];
    int t = threadIdx.x;
    int i = blockIdx.x * 256 + t;
    int v = (i < 2 * NG) ? GG[i] : 0;
    s[t] = v;
    __syncthreads();
    for (int off = 1; off < 256; off <<= 1) {
        int add = (t >= off) ? s[t - off] : 0;
        __syncthreads();
        s[t] += add;
        __syncthreads();
    }
    if (i < 2 * NG) Gs[i + 1] = s[t];
    if (t == 255) partials[blockIdx.x] = s[t];
}

__global__ void k_scanB(const int* __restrict__ partials, int* __restrict__ Gs) {
    __shared__ int s[256];
    int t = threadIdx.x;
    int p = 0;
    for (int j = t; j < (int)blockIdx.x; j += 256) p += partials[j];
    s[t] = p;
    __syncthreads();
    for (int off = 128; off > 0; off >>= 1) {
        if (t < off) s[t] += s[t + off];
        __syncthreads();
    }
    int prefix = s[0];
    int i = blockIdx.x * 256 + t;
    if (i < 2 * NG) Gs[i + 1] += prefix;
    if (blockIdx.x == 0 && t == 0) Gs[0] = 0;
}

// ---------------- pass 2: coarse scatter. dst side: packed (src | dl<<17) uint;
// src side: fine-bin bytes (Cls). ----------------
__global__ void k_pass2(const int* __restrict__ src, const int* __restrict__ dst,
                        const int* __restrict__ Gs, uint_t* __restrict__ Cpk,
                        uchar_t* __restrict__ Cls) {
    __shared__ int cur[NBUCK];
    __shared__ int cur2[NBUCK];
    int b = blockIdx.x;  // 391 blocks
    int t = threadIdx.x;
    for (int k = t; k < NBUCK; k += 256) {
        cur[k] = Gs[k * NB_HIST + b];
        cur2[k] = Gs[NG + k * NB_HIST + b] - N_EDGES;
    }
    __syncthreads();
    int e0 = b * 4096;
    int e1 = min(e0 + 4096, N_EDGES);
    for (int i = e0 + t; i < e1; i += 256) {
        int d = dst[i];
        int s = src[i];
        int slot = atomicAdd(&cur[d >> 7], 1);
        Cpk[slot] = (uint_t)s | ((uint_t)(d & 127) << 17);
        int slot2 = atomicAdd(&cur2[s >> 7], 1);
        Cls[slot2] = (uchar_t)(s & 127);
    }
}

// ---------------- pass 3, dual partition:
// blocks [0,NBUCK): dst-side fine build (rowptr/pdeg/nd + esrc)
// blocks [NBUCK,2*NBUCK): src-side fine histogram -> ns, then fused embed+prescale ----------------
__global__ void k_fine(const uint_t* __restrict__ Cpk, const uchar_t* __restrict__ Cls,
                       const int* __restrict__ Gs,
                       const int* __restrict__ tokens, const float* __restrict__ embed,
                       int* __restrict__ esrc, int* __restrict__ rowptr,
                       int* __restrict__ pdeg, float* __restrict__ ns,
                       float* __restrict__ nd, ushort_t* __restrict__ bufA) {
    __shared__ int hcnt[128];
    __shared__ int hstart[128];
    __shared__ float lns[128];
    int b = blockIdx.x;
    int t = threadIdx.x;
    if (b < NBUCK) {  // dst side
        int k = b;
        int node0 = k * 128;
        int nn = min(128, N_NODES - node0);
        int S = Gs[k * NB_HIST];
        int E = Gs[(k + 1) * NB_HIST];
        if (t < 128) hcnt[t] = 0;
        __syncthreads();
        for (int i = S + t; i < E; i += 256) atomicAdd(&hcnt[Cpk[i] >> 17], 1);
        __syncthreads();
        if (t == 0) {
            int acc = 0;
            for (int n = 0; n < nn; ++n) {
                hstart[n] = acc;
                acc += (hcnt[n] + 3) & ~3;
            }
        }
        __syncthreads();
        int base = (k * BUCK_RESERVE + S + 3) & ~3;
        if (t < nn) {
            int node = node0 + t;
            rowptr[node] = base + hstart[t];
            pdeg[node] = (hcnt[t] + 3) & ~3;
            nd[node] = rsqrtf(fmaxf((float)hcnt[t], 1.0f));
        }
        __syncthreads();
        for (int i = S + t; i < E; i += 256) {
            uint_t pk = Cpk[i];
            int slot = atomicAdd(&hstart[pk >> 17], 1);
            esrc[base + slot] = (int)(pk & 0x1FFFFu);
        }
    } else {  // src side -> ns, then fused embed gather + l0 prescale
        int k = b - NBUCK;
        int node0 = k * 128;
        int nn = min(128, N_NODES - node0);
        int S = Gs[NG + k * NB_HIST] - N_EDGES;
        int E = Gs[NG + (k + 1) * NB_HIST] - N_EDGES;
        if (t < 128) hcnt[t] = 0;
        __syncthreads();
        for (int i = S + t; i < E; i += 256) atomicAdd(&hcnt[Cls[i]], 1);
        __syncthreads();
        if (t < nn) {
            float v = rsqrtf(fmaxf((float)hcnt[t], 1.0f));
            ns[node0 + t] = v;
            lns[t] = v;
        }
        if (k == 0 && t == 0) ns[N_NODES] = 0.f;  // kills sentinel contributions
        __syncthreads();
        // fused embed + l0 prescale for this block's nodes
        for (int slot = t; slot < nn * 16; slot += 256) {
            int nloc = slot >> 4, sub = slot & 15;
            int node = node0 + nloc;
            float s = lns[nloc];
            const float* ep = embed + (size_t)tokens[node] * DIM + sub * 8;
            float4 a = *(const float4*)ep;
            float4 c = *(const float4*)(ep + 4);
            uint4 o;
            o.x = pack2(a.x * s, a.y * s);
            o.y = pack2(a.z * s, a.w * s);
            o.z = pack2(c.x * s, c.y * s);
            o.w = pack2(c.z * s, c.w * s);
            *(uint4*)(bufA + (size_t)node * DIM + sub * 8) = o;
        }
    }
}

// ---------------- prescale: x[v] = relu(fma(y,a,c)) * ns[v], bf16 (BN layers) ----------------
__global__ void k_prescale(const ushort_t* __restrict__ yin, const float* __restrict__ ns,
                           const float* __restrict__ bnsum, const float* __restrict__ bnsq,
                           const float* __restrict__ g, const float* __restrict__ be,
                           ushort_t* __restrict__ xout) {
    __shared__ float sa[DIM], sc[DIM];
    int t = threadIdx.x;
    if (t < DIM) {
        float mu = bnsum[t] * (1.0f / N_NODES);
        float var = bnsq[t] * (1.0f / N_NODES) - mu * mu;
        float rstd = rsqrtf(var + BN_EPS);
        float a = g[t] * rstd;
        sa[t] = a;
        sc[t] = be[t] - mu * a;
    }
    __syncthreads();
    int gid = blockIdx.x * 256 + t;  // 6250 blocks * 256 = N*16 exactly
    int node = gid >> 4, sub = gid & 15;
    float s = ns[node];
    uint4 u = *(const uint4*)(yin + (size_t)node * DIM + sub * 8);
    float v[8] = {bfl(u.x), bfh(u.x), bfl(u.y), bfh(u.y),
                  bfl(u.z), bfh(u.z), bfl(u.w), bfh(u.w)};
    const float* a = sa + sub * 8;
    const float* c = sc + sub * 8;
#pragma unroll
    for (int i = 0; i < 8; ++i) v[i] = fmaxf(fmaf(v[i], a[i], c[i]), 0.f) * s;
    uint4 o;
    o.x = pack2(v[0], v[1]); o.y = pack2(v[2], v[3]);
    o.z = pack2(v[4], v[5]); o.w = pack2(v[6], v[7]);
    *(uint4*)(xout + (size_t)node * DIM + sub * 8) = o;
}

// ---------------- FUSED gather -> LDS -> MFMA + BN stats.
// Gather is ONE continuous 4-deep software pipeline per wave over the wave's
// ENTIRE contiguous esrc span (16 nodes' rows are adjacent within a bucket;
// rows x4-padded => trip boundaries == node boundaries). Lane layout:
// quad = lane>>4 picks one of 4 edges per trip, m16 = lane&15 covers 16B of
// the 256B feature row -> one global_load_dwordx4 fetches 4 full rows (1KB)
// per wave-instruction. Features stay 4 trips (4KB/wave) in flight at ~100%
// duty; indices prefetched 8 trips ahead. Prefetch overrun past the span is
// sentinel-safe (esrc pad -> zero feature row). Node-boundary flush
// (wave-uniform branch, ~16 per ~76 trips): cross-quad shfl_xor(16/32)
// reduce, nd scale, quad0 writes the 16B LDS row. No barrier before MFMA
// (rows are wave-private). ----------------
__global__ __launch_bounds__(256) void k_agggemm(const ushort_t* __restrict__ hs,
        const int* __restrict__ rowptr, const int* __restrict__ pdeg,
        const int* __restrict__ esrc, const float* __restrict__ nd,
        const ushort_t* __restrict__ wbt, const float* __restrict__ bias,
        ushort_t* __restrict__ y,
        float* __restrict__ bnsum, float* __restrict__ bnsq) {
    __shared__ ushort_t at[64 * AT_STRIDE];
    __shared__ float csum[DIM], csq[DIM];
    int tid = threadIdx.x;
    int wave = tid >> 6;
    int lane = tid & 63;
    if (tid < DIM) { csum[tid] = 0.f; csq[tid] = 0.f; }
    __syncthreads();  // startup-only barrier

    int bnode = blockIdx.x * 64 + wave * 16;
    int quad = lane >> 4;   // edge slot within a trip (0..3)
    int m16 = lane & 15;    // 16B chunk within the 256B row

    const ushort_t* hrow = hs + (size_t)m16 * 8;  // lane's column offset

    // per-wave node metadata in lanes 0..15, served via shfl
    int rpv = 0, epv = 0;
    float ndv = 0.f;
    if (lane < 16) {
        int nnode = bnode + lane;
        if (nnode < N_NODES) {
            rpv = rowptr[nnode];
            epv = rpv + pdeg[nnode];
            ndv = nd[nnode];
        }
    }
    int ws = __shfl(rpv, 0);              // wave's first slot (x4-aligned)
    int T = (__shfl(epv, 15) - ws) >> 2;  // total trips for this wave

#define FEATLD(ix) (*(const uint4*)(hrow + (size_t)(ix) * DIM))
#define ACCU(F)                                                     \
    {                                                               \
        a[0] += bfl((F).x); a[1] += bfh((F).x);                     \
        a[2] += bfl((F).y); a[3] += bfh((F).y);                     \
        a[4] += bfl((F).z); a[5] += bfh((F).z);                     \
        a[6] += bfl((F).w); a[7] += bfh((F).w);                     \
    }
#define FLUSH()                                                     \
    {                                                               \
        float nv = __shfl(ndv, ni);                                 \
        _Pragma("unroll")                                           \
        for (int j = 0; j < 8; ++j) {                               \
            a[j] += __shfl_xor(a[j], 16);                           \
            a[j] += __shfl_xor(a[j], 32);                           \
        }                                                           \
        if (quad == 0) {                                            \
            uint4 o;                                                \
            o.x = pack2(a[0] * nv, a[1] * nv);                      \
            o.y = pack2(a[2] * nv, a[3] * nv);                      \
            o.z = pack2(a[4] * nv, a[5] * nv);                      \
            o.w = pack2(a[6] * nv, a[7] * nv);                      \
            *(uint4*)&at[(wave * 16 + ni) * AT_STRIDE + m16 * 8] = o; \
        }                                                           \
        _Pragma("unroll")                                           \
        for (int j = 0; j < 8; ++j) a[j] = 0.f;                     \
    }
// after consuming a trip, pos = base of the NEXT slot; flush completed nodes
// (wave-uniform: pos/end_cur identical across lanes)
#define BCHK()                                                      \
    while (ni < 16 && pos >= end_cur) {                             \
        FLUSH();                                                    \
        ++ni;                                                       \
        end_cur = __shfl(epv, ni < 16 ? ni : 15);                   \
    }

    float a[8] = {0.f, 0.f, 0.f, 0.f, 0.f, 0.f, 0.f, 0.f};
    int ni = 0;                       // current node (0..15) within wave
    int end_cur = __shfl(epv, 0);
    int pos = ws + 4;

    // ---- pipeline prologue: features for trips 0..3, indices for trips 4..7
    int sl = ws + quad;
    int i0 = esrc[sl], i1 = esrc[sl + 4], i2 = esrc[sl + 8], i3 = esrc[sl + 12];
    uint4 f0 = FEATLD(i0), f1 = FEATLD(i1), f2 = FEATLD(i2), f3 = FEATLD(i3);
    i0 = esrc[sl + 16]; i1 = esrc[sl + 20]; i2 = esrc[sl + 24]; i3 = esrc[sl + 28];
    sl += 32;

    // ---- steady state: consume trip t, re-issue its register set for t+4,
    // prefetch index for t+8
    int t = 0;
    for (; t + 4 <= T; t += 4) {
        { int n_ = esrc[sl]; sl += 4; ACCU(f0); f0 = FEATLD(i0); i0 = n_; BCHK(); pos += 4; }
        { int n_ = esrc[sl]; sl += 4; ACCU(f1); f1 = FEATLD(i1); i1 = n_; BCHK(); pos += 4; }
        { int n_ = esrc[sl]; sl += 4; ACCU(f2); f2 = FEATLD(i2); i2 = n_; BCHK(); pos += 4; }
        { int n_ = esrc[sl]; sl += 4; ACCU(f3); f3 = FEATLD(i3); i3 = n_; BCHK(); pos += 4; }
    }
    // ---- epilogue: up to 3 leftover trips
    if (t + 0 < T) { ACCU(f0); BCHK(); pos += 4; }
    if (t + 1 < T) { ACCU(f1); BCHK(); pos += 4; }
    if (t + 2 < T) { ACCU(f2); BCHK(); pos += 4; }
    // flush any remaining nodes (zero-degree / out-of-range tails)
    while (ni < 16) { FLUSH(); ++ni; }
#undef BCHK
#undef FLUSH
#undef ACCU
#undef FEATLD
    // NO barrier: each wave's MFMA reads only its own 16 LDS rows.

    // ---- phase 2: MFMA (D: col=lane&15, row=quad*4+reg) ----
    f32x4 acc[8];
#pragma unroll
    for (int nb = 0; nb < 8; ++nb) acc[nb] = (f32x4)(0.f);

    const ushort_t* ap = &at[(wave * 16 + m16) * AT_STRIDE + quad * 8];
#pragma unroll
    for (int k0b = 0; k0b < 4; ++k0b) {
        bf16x8 af = *(const bf16x8*)(ap + k0b * 32);
#pragma unroll
        for (int nb = 0; nb < 8; ++nb) {
            int ncol = nb * 16 + m16;
            bf16x8 bfg = *(const bf16x8*)(wbt + (size_t)ncol * DIM + k0b * 32 + quad * 8);
            acc[nb] = __builtin_amdgcn_mfma_f32_16x16x32_bf16(af, bfg, acc[nb], 0, 0, 0);
        }
    }

    // epilogue: bias, block-shared BN partial stats (LDS atomics), bf16 store
#pragma unroll
    for (int nb = 0; nb < 8; ++nb) {
        int col = nb * 16 + m16;
        float bcol = bias[col];
        float ps = 0.f, pq = 0.f;
#pragma unroll
        for (int reg = 0; reg < 4; ++reg) {
            int r = bnode + quad * 4 + reg;
            if (r < N_NODES) {
                float v = acc[nb][reg] + bcol;
                ps += v; pq += v * v;
                y[(size_t)r * DIM + col] = f2bf(v);
            }
        }
        atomicAdd(&csum[col], ps);
        atomicAdd(&csq[col], pq);
    }
    __syncthreads();  // final barrier: stats complete before global reduce
    if (tid < DIM) {
        atomicAdd(&bnsum[tid], csum[tid]);
        atomicAdd(&bnsq[tid], csq[tid]);
    }
}

// ---------------- pooling: fused layer-3 BN fold+apply + graph counts ----------------
#define POOL_NODES 128
__global__ void k_pool(const ushort_t* __restrict__ yin, const int* __restrict__ gids,
                       const float* __restrict__ bnsum, const float* __restrict__ bnsq,
                       const float* __restrict__ g, const float* __restrict__ be,
                       float* __restrict__ pool, int* __restrict__ cnt) {
    __shared__ int h[N_GRAPHS];
    int col = threadIdx.x;  // 128
    float mu = bnsum[col] * (1.0f / N_NODES);
    float var = bnsq[col] * (1.0f / N_NODES) - mu * mu;
    float rstd = rsqrtf(var + BN_EPS);
    float a = g[col] * rstd;
    float c = be[col] - mu * a;
    if (col < N_GRAPHS) h[col] = 0;
    __syncthreads();
    int base = blockIdx.x * POOL_NODES;
    int end = min(base + POOL_NODES, N_NODES);
    for (int n = base + col; n < end; n += 128) atomicAdd(&h[gids[n]], 1);
    __syncthreads();
    if (col < N_GRAPHS && h[col]) atomicAdd(&cnt[col], h[col]);
    float acc = 0.f;
    int cur = gids[base];
    for (int n = base; n < end; ++n) {
        int gg = gids[n];
        if (gg != cur) {
            atomicAdd(&pool[(size_t)cur * DIM + col], acc);
            acc = 0.f;
            cur = gg;
        }
        uint_t u = *(const uint_t*)(yin + (size_t)n * DIM + (col & ~1));
        float v = (col & 1) ? bfh(u) : bfl(u);
        acc += fmaxf(fmaf(v, a, c), 0.f);
    }
    atomicAdd(&pool[(size_t)cur * DIM + col], acc);
}

// ---------------- final FC (one block per graph) ----------------
__global__ void k_final(const float* __restrict__ pool, const int* __restrict__ cnt,
                        const float* __restrict__ fcW1, const float* __restrict__ fcb1,
                        const float* __restrict__ fcW2, const float* __restrict__ fcb2,
                        float* __restrict__ out) {
    __shared__ float hg[DIM];
    __shared__ float z[64];
    int g = blockIdx.x;
    int t = threadIdx.x;  // 128
    float cf = fmaxf((float)cnt[g], 1.0f);
    hg[t] = pool[(size_t)g * DIM + t] / cf;
    __syncthreads();
    if (t < 64) {
        float acc = fcb1[t];
        for (int k = 0; k < DIM; ++k)
            acc += hg[k] * fcW1[k * 64 + t];
        z[t] = fmaxf(acc, 0.f);
    }
    __syncthreads();
    if (t < 2) {
        float acc = fcb2[t];
        for (int k = 0; k < 64; ++k)
            acc += z[k] * fcW2[k * 2 + t];
        out[g * 2 + t] = acc;
    }
}

extern "C" void kernel_launch(void* const* d_in, const int* in_sizes, int n_in,
                              void* d_out, int out_size, void* d_ws, size_t ws_size,
                              hipStream_t stream) {
    const int* tokens = (const int*)d_in[0];
    const int* src = (const int*)d_in[1];
    const int* dst = (const int*)d_in[2];
    const int* gids = (const int*)d_in[3];
    const float* embed = (const float*)d_in[4];
    const float* W1 = (const float*)d_in[5];
    const float* b1 = (const float*)d_in[6];
    const float* g1 = (const float*)d_in[7];
    const float* be1 = (const float*)d_in[8];
    const float* W2 = (const float*)d_in[9];
    const float* b2 = (const float*)d_in[10];
    const float* g2 = (const float*)d_in[11];
    const float* be2 = (const float*)d_in[12];
    const float* W3 = (const float*)d_in[13];
    const float* b3 = (const float*)d_in[14];
    const float* g3 = (const float*)d_in[15];
    const float* be3 = (const float*)d_in[16];
    const float* fcW1 = (const float*)d_in[17];
    const float* fcb1 = (const float*)d_in[18];
    const float* fcW2 = (const float*)d_in[19];
    const float* fcb2 = (const float*)d_in[20];
    float* out = (float*)d_out;

    char* w = (char*)d_ws;
    auto alloc = [&](size_t bytes) {
        void* p = (void*)w;
        w += (bytes + 255) & ~(size_t)255;
        return p;
    };
    ushort_t* bufH = (ushort_t*)alloc((size_t)(N_NODES + 1) * DIM * 2);  // y2
    ushort_t* bufA = (ushort_t*)alloc((size_t)(N_NODES + 1) * DIM * 2);  // prescaled gather input
    ushort_t* bufY = (ushort_t*)alloc((size_t)(N_NODES + 1) * DIM * 2);  // y1 / y3
    int* esrc = (int*)alloc((size_t)EPAD * 4);
    int* rowptr = (int*)alloc((size_t)N_NODES * 4);
    int* pdeg = (int*)alloc((size_t)N_NODES * 4);
    float* ns = (float*)alloc((size_t)(N_NODES + 1) * 4);
    float* nd = (float*)alloc((size_t)N_NODES * 4);
    ushort_t* wbt = (ushort_t*)alloc(3 * DIM * DIM * 2);
    int* GG = (int*)alloc((size_t)(2 * NG) * 4);
    int* Gs = (int*)alloc((size_t)(2 * NG + 1) * 4);
    int* partials = (int*)alloc(4096 * 4);
    uint_t* Cpk = (uint_t*)alloc((size_t)N_EDGES * 4);
    uchar_t* Cls = (uchar_t*)alloc((size_t)N_EDGES);
    // zeroed region (contiguous)
    char* zstart = w;
    float* bnsum = (float*)alloc(3 * DIM * 4);
    float* bnsq = (float*)alloc(3 * DIM * 4);
    float* pool = (float*)alloc((size_t)N_GRAPHS * DIM * 4);
    int* cnt = (int*)alloc((size_t)N_GRAPHS * 4);
    int zwords = (int)((size_t)(w - zstart) / 4);

    k_front<<<NB_SENT + NB_WPREP + NB_HIST + NB_ZERO, 256, 0, stream>>>(
        src, dst, bufA, esrc, W1, W2, W3, wbt, GG, (int*)zstart, zwords);
    k_scanA<<<NB_SCANG2, 256, 0, stream>>>(GG, Gs, partials);
    k_scanB<<<NB_SCANG2, 256, 0, stream>>>(partials, Gs);
    k_pass2<<<NB_HIST, 256, 0, stream>>>(src, dst, Gs, Cpk, Cls);
    k_fine<<<2 * NBUCK, 256, 0, stream>>>(Cpk, Cls, Gs, tokens, embed,
                                          esrc, rowptr, pdeg, ns, nd, bufA);

    int nb_fused = (N_NODES + 63) / 64;  // 256-thread blocks, 64 nodes each
    int nb_ps = 6250;                    // N*16/256

    // l=0: bufA already holds embed*ns (fused into k_fine); gather -> y1 in bufY
    k_agggemm<<<nb_fused, 256, 0, stream>>>(bufA, rowptr, pdeg, esrc, nd,
                                            wbt, b1, bufY, bnsum, bnsq);
    // l=1: prescale bufY (BN stats1) -> bufA; gather -> y2 in bufH
    k_prescale<<<nb_ps, 256, 0, stream>>>(bufY, ns, bnsum, bnsq, g1, be1, bufA);
    k_agggemm<<<nb_fused, 256, 0, stream>>>(bufA, rowptr, pdeg, esrc, nd,
                                            wbt + (size_t)DIM * DIM, b2, bufH,
                                            bnsum + DIM, bnsq + DIM);
    // l=2: prescale bufH (BN stats2) -> bufA; gather -> y3 in bufY
    k_prescale<<<nb_ps, 256, 0, stream>>>(bufH, ns, bnsum + DIM, bnsq + DIM, g2, be2, bufA);
    k_agggemm<<<nb_fused, 256, 0, stream>>>(bufA, rowptr, pdeg, esrc, nd,
                                            wbt + (size_t)2 * DIM * DIM, b3, bufY,
                                            bnsum + 2 * DIM, bnsq + 2 * DIM);

    k_pool<<<(N_NODES + POOL_NODES - 1) / POOL_NODES, DIM, 0, stream>>>(
        bufY, gids, bnsum + 2 * DIM, bnsq + 2 * DIM, g3, be3, pool, cnt);
    k_final<<<N_GRAPHS, DIM, 0, stream>>>(pool, cnt, fcW1, fcb1, fcW2, fcb2, out);
}